// Round 8
// baseline (252.664 us; speedup 1.0000x reference)
//
#include <hip/hip_runtime.h>
#include <hip/hip_bf16.h>

#define XD 256   // input feature dim
#define HH 8     // heads
#define DD 128   // per-head dim
#define ZD 64    // latent dim
#define CAP 64   // max in-degree bucket capacity (mean deg=9, P(>=64) ~ 1e-30)
#define AGGB 2560 // blocks for aggregation kernel (10240 waves, ~2 nodes/wave)
#define REDB 64   // blocks for partial-reduce kernel
#define LOG2E 1.44269504088896340736f

using f32x4 = __attribute__((ext_vector_type(4))) float;
using s16x8 = __attribute__((ext_vector_type(8))) short;

static __device__ __forceinline__ float bf2f(unsigned short u) {
    union { unsigned int i; float f; } v; v.i = ((unsigned int)u) << 16; return v.f;
}
static __device__ __forceinline__ unsigned short f2bf(float f) {
    union { float f; unsigned int i; } v; v.f = f;
    unsigned int r = v.i + 0x7FFFu + ((v.i >> 16) & 1u);  // round-to-nearest-even
    return (unsigned short)(r >> 16);
}
static __device__ __forceinline__ void gload_lds16(const void* g, void* l) {
    __builtin_amdgcn_global_load_lds(
        (const __attribute__((address_space(1))) unsigned int*)g,
        (__attribute__((address_space(3))) unsigned int*)l, 16, 0, 0);
}
static __device__ __forceinline__ void fatomic_add(float* p, float v) {
    __hip_atomic_fetch_add(p, v, __ATOMIC_RELAXED, __HIP_MEMORY_SCOPE_AGENT);
}

// ---------------- prep: x->bf16 (padded), W->W^T bf16, res_W -> head-summed ^T bf16, bias head-sum
__global__ void prep_kernel(const float* __restrict__ x, const float* __restrict__ W,
                            const float* __restrict__ resW, const float* __restrict__ bias,
                            unsigned short* __restrict__ xb, unsigned short* __restrict__ wtb,
                            unsigned short* __restrict__ rwtb, float* __restrict__ bias_sum,
                            int N, int NPAD) {
    long long i = (long long)blockIdx.x * blockDim.x + threadIdx.x;
    long long nx4 = (long long)NPAD * XD / 4;
    if (i < nx4) {
        long long e = i * 4;
        long long lim = (long long)N * XD;
        float4 v = {0.f, 0.f, 0.f, 0.f};
        if (e < lim) v = *(const float4*)(x + e);  // N*XD is a multiple of 4
        ushort4 o; o.x = f2bf(v.x); o.y = f2bf(v.y); o.z = f2bf(v.z); o.w = f2bf(v.w);
        *(ushort4*)(xb + e) = o;
        return;
    }
    i -= nx4;
    if (i < XD * HH * DD) {        // W^T: wtb[col][k] = W[k][col]
        int col = (int)(i >> 8), k = (int)(i & 255);
        wtb[i] = f2bf(W[(long long)k * (HH * DD) + col]);
        return;
    }
    i -= XD * HH * DD;
    if (i < DD * XD) {             // rwtb[d][k] = sum_h resW[k][h*DD+d]
        int d = (int)(i >> 8), k = (int)(i & 255);
        float s = 0.f;
        #pragma unroll
        for (int h = 0; h < HH; ++h) s += resW[(long long)k * (HH * DD) + h * DD + d];
        rwtb[i] = f2bf(s);
        return;
    }
    i -= DD * XD;
    if (i < DD) {
        float s = 0.f;
        #pragma unroll
        for (int h = 0; h < HH; ++h) s += bias[h * DD + (int)i];
        bias_sum[i] = s;
    }
}

// ---------------- gemm1: feat = x@W (bf16 out) + el/er epilogue; blockIdx.y==8 -> hres = x@res_W_sum
// NOTE: el/er are accumulated PRE-SCALED by log2(e) so agg can use exp2 directly.
__global__ __launch_bounds__(256) void gemm1_kernel(
    const unsigned short* __restrict__ xb,    // [NPAD][256] bf16
    const unsigned short* __restrict__ wtb,   // [1024][256] bf16 (W^T)
    const unsigned short* __restrict__ rwtb,  // [128][256]  bf16 (res_W_sum^T)
    const float* __restrict__ attn_l, const float* __restrict__ attn_r,  // [8][128]
    unsigned short* __restrict__ featb,       // [N][1024] bf16
    float* __restrict__ hres,                 // [N][128]
    float* __restrict__ el, float* __restrict__ er,  // [N][8] (atomic accum, pre-zeroed)
    int N) {
    __shared__ unsigned short As[128 * 64];
    __shared__ unsigned short Bs[128 * 64];
    const int tid = threadIdx.x;
    const int lane = tid & 63;
    const int wid = tid >> 6;
    const int wm = wid >> 1, wn = wid & 1;
    const int brow = blockIdx.x * 128;
    const int y = blockIdx.y;  // 0..7 = head blocks, 8 = residual block
    const unsigned short* bsrc = (y < 8) ? (wtb + y * 128 * 256) : rwtb;

    f32x4 acc[4][4] = {};
    for (int kt = 0; kt < 4; ++kt) {
        #pragma unroll
        for (int it = 0; it < 4; ++it) {
            int c = it * 256 + tid;            // 16B chunk id, 0..1023
            int row = c >> 3, kc = c & 7;
            gload_lds16(xb  + (brow + row) * 256 + kt * 64 + kc * 8, (char*)As + c * 16);
            gload_lds16(bsrc + row * 256 + kt * 64 + kc * 8,          (char*)Bs + c * 16);
        }
        __syncthreads();
        #pragma unroll
        for (int ks = 0; ks < 2; ++ks) {
            s16x8 a[4], b[4];
            #pragma unroll
            for (int m = 0; m < 4; ++m)
                a[m] = *(const s16x8*)(As + (wm * 64 + m * 16 + (lane & 15)) * 64 + ks * 32 + (lane >> 4) * 8);
            #pragma unroll
            for (int n = 0; n < 4; ++n)
                b[n] = *(const s16x8*)(Bs + (wn * 64 + n * 16 + (lane & 15)) * 64 + ks * 32 + (lane >> 4) * 8);
            #pragma unroll
            for (int m = 0; m < 4; ++m)
                #pragma unroll
                for (int n = 0; n < 4; ++n)
                    acc[m][n] = __builtin_amdgcn_mfma_f32_16x16x32_bf16(a[m], b[n], acc[m][n], 0, 0, 0);
        }
        __syncthreads();
    }

    if (y < 8) {
        float al[4], ar[4];
        #pragma unroll
        for (int n = 0; n < 4; ++n) {
            int colh = wn * 64 + n * 16 + (lane & 15);
            al[n] = attn_l[y * 128 + colh] * LOG2E;
            ar[n] = attn_r[y * 128 + colh] * LOG2E;
        }
        #pragma unroll
        for (int m = 0; m < 4; ++m) {
            #pragma unroll
            for (int j = 0; j < 4; ++j) {
                int row = brow + wm * 64 + m * 16 + (lane >> 4) * 4 + j;
                float pel = 0.f, per = 0.f;
                #pragma unroll
                for (int n = 0; n < 4; ++n) { pel += acc[m][n][j] * al[n]; per += acc[m][n][j] * ar[n]; }
                #pragma unroll
                for (int o = 1; o < 16; o <<= 1) { pel += __shfl_xor(pel, o); per += __shfl_xor(per, o); }
                if ((lane & 15) == 0 && row < N) {
                    fatomic_add(el + row * 8 + y, pel);
                    fatomic_add(er + row * 8 + y, per);
                }
            }
        }
        #pragma unroll
        for (int m = 0; m < 4; ++m)
            #pragma unroll
            for (int n = 0; n < 4; ++n)
                #pragma unroll
                for (int j = 0; j < 4; ++j) {
                    int row = brow + wm * 64 + m * 16 + (lane >> 4) * 4 + j;
                    if (row < N) {
                        int col = y * 128 + wn * 64 + n * 16 + (lane & 15);
                        featb[(long long)row * 1024 + col] = f2bf(acc[m][n][j]);
                    }
                }
    } else {
        #pragma unroll
        for (int m = 0; m < 4; ++m)
            #pragma unroll
            for (int n = 0; n < 4; ++n)
                #pragma unroll
                for (int j = 0; j < 4; ++j) {
                    int row = brow + wm * 64 + m * 16 + (lane >> 4) * 4 + j;
                    if (row < N) {
                        int col = wn * 64 + n * 16 + (lane & 15);
                        hres[(long long)row * 128 + col] = acc[m][n][j];
                    }
                }
    }
}

// ---------------- bucket: group edges by dst, storing SRC node id (w recomputed in agg)
__global__ void bucket_kernel(const int* __restrict__ src, const int* __restrict__ dst,
                              int* __restrict__ cnt, int* __restrict__ bucket, int E) {
    int e = blockIdx.x * blockDim.x + threadIdx.x;
    if (e >= E) return;
    int sN = src[e], dN = dst[e];
    int idx = atomicAdd(cnt + dN, 1);
    if (idx < CAP) bucket[dN * CAP + idx] = sN;
}

// ---------------- agg: one wave per dst node; fused softmax (denominator in-registers)
__global__ __launch_bounds__(256) void agg_kernel(
    const unsigned short* __restrict__ featb,
    const float* __restrict__ el, const float* __restrict__ er,
    const int* __restrict__ cnt, const int* __restrict__ bucket,
    const float* __restrict__ hres, const float* __restrict__ bias_sum,
    unsigned short* __restrict__ hbf, float* __restrict__ partial, int N) {
    const int lane = threadIdx.x & 63;
    const int wv = threadIdx.x >> 6;
    const int d0 = lane * 2;
    float psum0 = 0.f, psq0 = 0.f, psum1 = 0.f, psq1 = 0.f;
    for (int n = blockIdx.x * 4 + wv; n < N; n += gridDim.x * 4) {
        float4 er0 = *(const float4*)(er + n * 8);
        float4 er1 = *(const float4*)(er + n * 8 + 4);
        float erv[8] = {er0.x, er0.y, er0.z, er0.w, er1.x, er1.y, er1.z, er1.w};
        int c = cnt[n]; if (c > CAP) c = CAP;
        float sden[8] = {0.f, 0.f, 0.f, 0.f, 0.f, 0.f, 0.f, 0.f};
        float a0h[8] = {0.f, 0.f, 0.f, 0.f, 0.f, 0.f, 0.f, 0.f};
        float a1h[8] = {0.f, 0.f, 0.f, 0.f, 0.f, 0.f, 0.f, 0.f};
        int s_nx = 0;
        if (c > 0) s_nx = bucket[n * CAP];           // 1-deep prefetch
        for (int i = 0; i < c; ++i) {
            int sn = s_nx;
            if (i + 1 < c) s_nx = bucket[n * CAP + i + 1];
            float4 el0 = *(const float4*)(el + sn * 8);
            float4 el1 = *(const float4*)(el + sn * 8 + 4);
            float elv[8] = {el0.x, el0.y, el0.z, el0.w, el1.x, el1.y, el1.z, el1.w};
            float wh[8];
            #pragma unroll
            for (int h = 0; h < 8; ++h) {
                float v = elv[h] + erv[h];            // pre-scaled by log2(e)
                v = fmaxf(v, 0.2f * v);               // leaky_relu(x,0.2) == max(x, 0.2x)
                wh[h] = __builtin_exp2f(v);           // single v_exp_f32
                sden[h] += wh[h];
            }
            const unsigned short* fb = featb + (long long)sn * 1024 + d0;
            #pragma unroll
            for (int h = 0; h < 8; ++h) {
                unsigned int u = *(const unsigned int*)(fb + h * 128);
                union { unsigned int i; float f; } cl, ch;
                cl.i = u << 16;                       // low bf16 -> f32 (1 op)
                ch.i = u & 0xffff0000u;               // high bf16 -> f32 (1 op)
                a0h[h] += wh[h] * cl.f;
                a1h[h] += wh[h] * ch.f;
            }
        }
        float a0 = 0.f, a1 = 0.f;
        #pragma unroll
        for (int h = 0; h < 8; ++h) {
            float inv = 1.f / sden[h];
            a0 += a0h[h] * inv;
            a1 += a1h[h] * inv;
        }
        float h0 = a0 + hres[n * 128 + d0]     + bias_sum[d0];
        float h1 = a1 + hres[n * 128 + d0 + 1] + bias_sum[d0 + 1];
        h0 = h0 > 0.f ? h0 : 0.f;
        h1 = h1 > 0.f ? h1 : 0.f;
        unsigned int pack = (unsigned int)f2bf(h0) | ((unsigned int)f2bf(h1) << 16);
        *(unsigned int*)(hbf + (long long)n * 128 + d0) = pack;
        psum0 += h0; psq0 += h0 * h0; psum1 += h1; psq1 += h1 * h1;
    }
    __shared__ float red[4][64][4];
    red[wv][lane][0] = psum0; red[wv][lane][1] = psq0;
    red[wv][lane][2] = psum1; red[wv][lane][3] = psq1;
    __syncthreads();
    if (wv == 0) {
        float t0 = 0.f, t1 = 0.f, t2 = 0.f, t3 = 0.f;
        #pragma unroll
        for (int k = 0; k < 4; ++k) {
            t0 += red[k][lane][0]; t1 += red[k][lane][1];
            t2 += red[k][lane][2]; t3 += red[k][lane][3];
        }
        *(float4*)(partial + (blockIdx.x * 64 + lane) * 4) = make_float4(t0, t1, t2, t3);
    }
}

// ---------------- reduce: partial[AGGB][256] -> fin[256] via 64 blocks + atomics
__global__ __launch_bounds__(256) void reduce_kernel(const float* __restrict__ partial,
                                                     float* __restrict__ fin, int nblk) {
    const int t = threadIdx.x;
    const int rows = (nblk + gridDim.x - 1) / gridDim.x;
    const int b0 = blockIdx.x * rows;
    float a0 = 0.f, a1 = 0.f, a2 = 0.f, a3 = 0.f;
    for (int u = 0; u + 3 < rows; u += 4) {
        int bb = b0 + u;
        if (bb + 3 < nblk) {
            a0 += partial[(long long)bb * 256 + t];
            a1 += partial[(long long)(bb + 1) * 256 + t];
            a2 += partial[(long long)(bb + 2) * 256 + t];
            a3 += partial[(long long)(bb + 3) * 256 + t];
        } else {
            for (int k = 0; k < 4 && bb + k < nblk; ++k) a0 += partial[(long long)(bb + k) * 256 + t];
        }
    }
    for (int u = rows & ~3; u < rows; ++u)
        if (b0 + u < nblk) a0 += partial[(long long)(b0 + u) * 256 + t];
    fatomic_add(fin + t, (a0 + a1) + (a2 + a3));
}

// ---------------- fold: BN scale/shift -> bf16 folded weights Wcat[col][k] + fp32 folded biases
__global__ __launch_bounds__(1024) void fold_kernel(
    const float* __restrict__ fin,
    const float* __restrict__ gamma, const float* __restrict__ beta,
    const float* __restrict__ muW, const float* __restrict__ mub,
    const float* __restrict__ lsW, const float* __restrict__ lsb,
    unsigned short* __restrict__ wcat, float* __restrict__ bcat, int N) {
    __shared__ float sc_s[128], sh_s[128];
    __shared__ float redA[1024];
    const int t = threadIdx.x;
    if (t < 128) {
        float sum = fin[(t >> 1) * 4 + (t & 1) * 2];
        float sq  = fin[(t >> 1) * 4 + (t & 1) * 2 + 1];
        float mean = sum / (float)N;
        float var = sq / (float)N - mean * mean;        // biased var, matches jnp.var
        float rs = rsqrtf(var + 1e-5f);
        float sc = rs * gamma[t];
        sc_s[t] = sc;
        sh_s[t] = beta[t] - mean * sc;
    }
    __syncthreads();
    // wcat[c*128 + d] = bf16(sc[d] * W[d][c'])  (B-operand layout: [col][k])
    for (int i = t; i < 128 * 128; i += 1024) {
        int cc = i >> 7, d = i & 127;
        float wsrc = (cc < 64) ? muW[d * 64 + cc] : lsW[d * 64 + (cc - 64)];
        wcat[i] = f2bf(sc_s[d] * wsrc);
    }
    // bcat[c] = b[c'] + sum_d sh[d]*W[d][c']  -- 8 d-chunks x 128 cols, LDS reduce
    {
        int cc = t & 127, dc = t >> 7;
        float a = 0.f;
        #pragma unroll
        for (int u = 0; u < 16; ++u) {
            int d = dc * 16 + u;
            float wsrc = (cc < 64) ? muW[d * 64 + cc] : lsW[d * 64 + (cc - 64)];
            a += sh_s[d] * wsrc;
        }
        redA[t] = a;
    }
    __syncthreads();
    if (t < 128) {
        float b = (t < 64) ? mub[t] : lsb[t - 64];
        #pragma unroll
        for (int k = 0; k < 8; ++k) b += redA[k * 128 + t];
        bcat[t] = b;
    }
}

// ---------------- outgemm (MFMA): [mu|log_sigma] = hbf @ wcat + bcat, clip on ls half
__global__ __launch_bounds__(256) void outgemm_kernel(
    const unsigned short* __restrict__ hbf,   // [NPAD][128] bf16
    const unsigned short* __restrict__ wcat,  // [128 cols][128 k] bf16
    const float* __restrict__ bcat,           // [128]
    float* __restrict__ out, int N) {
    __shared__ unsigned short As[128 * 64];
    __shared__ unsigned short Bs[128 * 64];
    const int tid = threadIdx.x;
    const int lane = tid & 63;
    const int wid = tid >> 6;
    const int wm = wid >> 1, wn = wid & 1;
    const int brow = blockIdx.x * 128;

    f32x4 acc[4][4] = {};
    for (int kt = 0; kt < 2; ++kt) {
        #pragma unroll
        for (int it = 0; it < 4; ++it) {
            int c = it * 256 + tid;            // 16B chunk id, 0..1023
            int row = c >> 3, kc = c & 7;
            gload_lds16(hbf + (brow + row) * 128 + kt * 64 + kc * 8, (char*)As + c * 16);
            gload_lds16(wcat + row * 128 + kt * 64 + kc * 8,          (char*)Bs + c * 16);
        }
        __syncthreads();
        #pragma unroll
        for (int ks = 0; ks < 2; ++ks) {
            s16x8 a[4], b[4];
            #pragma unroll
            for (int m = 0; m < 4; ++m)
                a[m] = *(const s16x8*)(As + (wm * 64 + m * 16 + (lane & 15)) * 64 + ks * 32 + (lane >> 4) * 8);
            #pragma unroll
            for (int n = 0; n < 4; ++n)
                b[n] = *(const s16x8*)(Bs + (wn * 64 + n * 16 + (lane & 15)) * 64 + ks * 32 + (lane >> 4) * 8);
            #pragma unroll
            for (int m = 0; m < 4; ++m)
                #pragma unroll
                for (int n = 0; n < 4; ++n)
                    acc[m][n] = __builtin_amdgcn_mfma_f32_16x16x32_bf16(a[m], b[n], acc[m][n], 0, 0, 0);
        }
        __syncthreads();
    }

    float bc[4];
    #pragma unroll
    for (int n = 0; n < 4; ++n) bc[n] = bcat[wn * 64 + n * 16 + (lane & 15)];
    #pragma unroll
    for (int m = 0; m < 4; ++m)
        #pragma unroll
        for (int n = 0; n < 4; ++n) {
            int col = wn * 64 + n * 16 + (lane & 15);
            #pragma unroll
            for (int j = 0; j < 4; ++j) {
                int row = brow + wm * 64 + m * 16 + (lane >> 4) * 4 + j;
                if (row < N) {
                    float v = acc[m][n][j] + bc[n];
                    if (col < 64) {
                        out[(long long)row * 64 + col] = v;
                    } else {
                        v = fminf(fmaxf(v, -10.f), 10.f);
                        out[(long long)N * 64 + (long long)row * 64 + (col - 64)] = v;
                    }
                }
            }
        }
}

extern "C" void kernel_launch(void* const* d_in, const int* in_sizes, int n_in,
                              void* d_out, int out_size, void* d_ws, size_t ws_size,
                              hipStream_t stream) {
    const float* x      = (const float*)d_in[0];
    const float* W      = (const float*)d_in[1];
    const float* attn_l = (const float*)d_in[2];
    const float* attn_r = (const float*)d_in[3];
    const float* resW   = (const float*)d_in[4];
    const float* bias   = (const float*)d_in[5];
    const float* gamma  = (const float*)d_in[6];
    const float* beta   = (const float*)d_in[7];
    const float* muW    = (const float*)d_in[8];
    const float* mub    = (const float*)d_in[9];
    const float* lsW    = (const float*)d_in[10];
    const float* lsb    = (const float*)d_in[11];
    const int*   src    = (const int*)d_in[12];
    const int*   dst    = (const int*)d_in[13];

    const int N = in_sizes[0] / XD;
    const int E = in_sizes[12];
    const int NPAD = ((N + 127) / 128) * 128;

    char* p = (char*)d_ws;
    size_t off = 0;
    auto alloc = [&](size_t bytes) -> void* {
        void* r = p + off;
        off = (off + bytes + 255) & ~(size_t)255;
        return r;
    };
    unsigned short* xb   = (unsigned short*)alloc((size_t)NPAD * XD * 2);
    unsigned short* wtb  = (unsigned short*)alloc((size_t)XD * HH * DD * 2);
    unsigned short* rwtb = (unsigned short*)alloc((size_t)DD * XD * 2);
    float* bias_sum      = (float*)alloc(DD * 4);
    unsigned short* featb= (unsigned short*)alloc((size_t)N * HH * DD * 2);
    float* hres          = (float*)alloc((size_t)N * DD * 4);
    float* el            = (float*)alloc((size_t)N * HH * 4);   // zero region start
    float* er            = (float*)alloc((size_t)N * HH * 4);
    int*   cnt           = (int*)alloc((size_t)N * 4);
    float* fin           = (float*)alloc(256 * 4);              // zero region end
    int*   bucket        = (int*)alloc((size_t)N * CAP * 4);
    unsigned short* hbf  = (unsigned short*)alloc((size_t)NPAD * DD * 2);
    float* partial       = (float*)alloc((size_t)AGGB * 256 * 4);
    unsigned short* wcat = (unsigned short*)alloc(128 * 128 * 2);
    float* bcat          = (float*)alloc(128 * 4);

    // zero el|er|cnt|fin (exact byte span, alloc-rounding included)
    size_t zbytes = (size_t)((char*)bucket - (char*)el);
    hipMemsetAsync(el, 0, zbytes, stream);

    long long prep_total = (long long)NPAD * XD / 4 + XD * HH * DD + DD * XD + DD;
    int prep_blocks = (int)((prep_total + 255) / 256);
    prep_kernel<<<prep_blocks, 256, 0, stream>>>(x, W, resW, bias, xb, wtb, rwtb, bias_sum, N, NPAD);

    dim3 g1(NPAD / 128, HH + 1);
    gemm1_kernel<<<g1, 256, 0, stream>>>(xb, wtb, rwtb, attn_l, attn_r, featb, hres, el, er, N);

    bucket_kernel<<<(E + 255) / 256, 256, 0, stream>>>(src, dst, cnt, bucket, E);

    agg_kernel<<<AGGB, 256, 0, stream>>>(featb, el, er, cnt, bucket, hres, bias_sum,
                                         hbf, partial, N);

    reduce_kernel<<<REDB, 256, 0, stream>>>(partial, fin, AGGB);

    fold_kernel<<<1, 1024, 0, stream>>>(fin, gamma, beta, muW, mub, lsW, lsb, wcat, bcat, N);

    outgemm_kernel<<<NPAD / 128, 256, 0, stream>>>(hbf, wcat, bcat, (float*)d_out, N);
}

// Round 11
// 251.215 us; speedup vs baseline: 1.0058x; 1.0058x over previous
//
#include <hip/hip_runtime.h>
#include <hip/hip_bf16.h>

#define XD 256   // input feature dim
#define HH 8     // heads
#define DD 128   // per-head dim
#define ZD 64    // latent dim
#define CAP 64   // max in-degree bucket capacity (mean deg=9, P(>=64) ~ 1e-30)
#define AGGB 1280 // blocks for aggregation kernel
#define REDB 64   // blocks for partial-reduce kernel
#define LOG2E 1.44269504088896340736f

using f32x4 = __attribute__((ext_vector_type(4))) float;
using s16x8 = __attribute__((ext_vector_type(8))) short;

static __device__ __forceinline__ float bf2f(unsigned short u) {
    union { unsigned int i; float f; } v; v.i = ((unsigned int)u) << 16; return v.f;
}
static __device__ __forceinline__ unsigned short f2bf(float f) {
    union { float f; unsigned int i; } v; v.f = f;
    unsigned int r = v.i + 0x7FFFu + ((v.i >> 16) & 1u);  // round-to-nearest-even
    return (unsigned short)(r >> 16);
}
static __device__ __forceinline__ void gload_lds16(const void* g, void* l) {
    __builtin_amdgcn_global_load_lds(
        (const __attribute__((address_space(1))) unsigned int*)g,
        (__attribute__((address_space(3))) unsigned int*)l, 16, 0, 0);
}
static __device__ __forceinline__ void fatomic_add(float* p, float v) {
    __hip_atomic_fetch_add(p, v, __ATOMIC_RELAXED, __HIP_MEMORY_SCOPE_AGENT);
}

// ---------------- prep: x->bf16 (padded), W->W^T bf16, res_W -> head-summed ^T bf16, bias head-sum
__global__ void prep_kernel(const float* __restrict__ x, const float* __restrict__ W,
                            const float* __restrict__ resW, const float* __restrict__ bias,
                            unsigned short* __restrict__ xb, unsigned short* __restrict__ wtb,
                            unsigned short* __restrict__ rwtb, float* __restrict__ bias_sum,
                            int N, int NPAD) {
    long long i = (long long)blockIdx.x * blockDim.x + threadIdx.x;
    long long nx4 = (long long)NPAD * XD / 4;
    if (i < nx4) {
        long long e = i * 4;
        long long lim = (long long)N * XD;
        float4 v = {0.f, 0.f, 0.f, 0.f};
        if (e < lim) v = *(const float4*)(x + e);  // N*XD is a multiple of 4
        ushort4 o; o.x = f2bf(v.x); o.y = f2bf(v.y); o.z = f2bf(v.z); o.w = f2bf(v.w);
        *(ushort4*)(xb + e) = o;
        return;
    }
    i -= nx4;
    if (i < XD * HH * DD) {        // W^T: wtb[col][k] = W[k][col]
        int col = (int)(i >> 8), k = (int)(i & 255);
        wtb[i] = f2bf(W[(long long)k * (HH * DD) + col]);
        return;
    }
    i -= XD * HH * DD;
    if (i < DD * XD) {             // rwtb[d][k] = sum_h resW[k][h*DD+d]
        int d = (int)(i >> 8), k = (int)(i & 255);
        float s = 0.f;
        #pragma unroll
        for (int h = 0; h < HH; ++h) s += resW[(long long)k * (HH * DD) + h * DD + d];
        rwtb[i] = f2bf(s);
        return;
    }
    i -= DD * XD;
    if (i < DD) {
        float s = 0.f;
        #pragma unroll
        for (int h = 0; h < HH; ++h) s += bias[h * DD + (int)i];
        bias_sum[i] = s;
    }
}

// ---------------- gemm1: feat = x@W (bf16 out) + el/er epilogue; blockIdx.y==8 -> hres = x@res_W_sum
// NOTE: el/er are accumulated PRE-SCALED by log2(e) so agg can use exp2 directly.
__global__ __launch_bounds__(256) void gemm1_kernel(
    const unsigned short* __restrict__ xb,    // [NPAD][256] bf16
    const unsigned short* __restrict__ wtb,   // [1024][256] bf16 (W^T)
    const unsigned short* __restrict__ rwtb,  // [128][256]  bf16 (res_W_sum^T)
    const float* __restrict__ attn_l, const float* __restrict__ attn_r,  // [8][128]
    unsigned short* __restrict__ featb,       // [N][1024] bf16
    float* __restrict__ hres,                 // [N][128]
    float* __restrict__ el, float* __restrict__ er,  // [N][8] (atomic accum, pre-zeroed)
    int N) {
    __shared__ unsigned short As[128 * 64];
    __shared__ unsigned short Bs[128 * 64];
    const int tid = threadIdx.x;
    const int lane = tid & 63;
    const int wid = tid >> 6;
    const int wm = wid >> 1, wn = wid & 1;
    const int brow = blockIdx.x * 128;
    const int y = blockIdx.y;  // 0..7 = head blocks, 8 = residual block
    const unsigned short* bsrc = (y < 8) ? (wtb + y * 128 * 256) : rwtb;

    f32x4 acc[4][4] = {};
    for (int kt = 0; kt < 4; ++kt) {
        #pragma unroll
        for (int it = 0; it < 4; ++it) {
            int c = it * 256 + tid;            // 16B chunk id, 0..1023
            int row = c >> 3, kc = c & 7;
            gload_lds16(xb  + (brow + row) * 256 + kt * 64 + kc * 8, (char*)As + c * 16);
            gload_lds16(bsrc + row * 256 + kt * 64 + kc * 8,          (char*)Bs + c * 16);
        }
        __syncthreads();
        #pragma unroll
        for (int ks = 0; ks < 2; ++ks) {
            s16x8 a[4], b[4];
            #pragma unroll
            for (int m = 0; m < 4; ++m)
                a[m] = *(const s16x8*)(As + (wm * 64 + m * 16 + (lane & 15)) * 64 + ks * 32 + (lane >> 4) * 8);
            #pragma unroll
            for (int n = 0; n < 4; ++n)
                b[n] = *(const s16x8*)(Bs + (wn * 64 + n * 16 + (lane & 15)) * 64 + ks * 32 + (lane >> 4) * 8);
            #pragma unroll
            for (int m = 0; m < 4; ++m)
                #pragma unroll
                for (int n = 0; n < 4; ++n)
                    acc[m][n] = __builtin_amdgcn_mfma_f32_16x16x32_bf16(a[m], b[n], acc[m][n], 0, 0, 0);
        }
        __syncthreads();
    }

    if (y < 8) {
        float al[4], ar[4];
        #pragma unroll
        for (int n = 0; n < 4; ++n) {
            int colh = wn * 64 + n * 16 + (lane & 15);
            al[n] = attn_l[y * 128 + colh] * LOG2E;
            ar[n] = attn_r[y * 128 + colh] * LOG2E;
        }
        #pragma unroll
        for (int m = 0; m < 4; ++m) {
            #pragma unroll
            for (int j = 0; j < 4; ++j) {
                int row = brow + wm * 64 + m * 16 + (lane >> 4) * 4 + j;
                float pel = 0.f, per = 0.f;
                #pragma unroll
                for (int n = 0; n < 4; ++n) { pel += acc[m][n][j] * al[n]; per += acc[m][n][j] * ar[n]; }
                #pragma unroll
                for (int o = 1; o < 16; o <<= 1) { pel += __shfl_xor(pel, o); per += __shfl_xor(per, o); }
                if ((lane & 15) == 0 && row < N) {
                    fatomic_add(el + row * 8 + y, pel);
                    fatomic_add(er + row * 8 + y, per);
                }
            }
        }
        #pragma unroll
        for (int m = 0; m < 4; ++m)
            #pragma unroll
            for (int n = 0; n < 4; ++n)
                #pragma unroll
                for (int j = 0; j < 4; ++j) {
                    int row = brow + wm * 64 + m * 16 + (lane >> 4) * 4 + j;
                    if (row < N) {
                        int col = y * 128 + wn * 64 + n * 16 + (lane & 15);
                        featb[(long long)row * 1024 + col] = f2bf(acc[m][n][j]);
                    }
                }
    } else {
        #pragma unroll
        for (int m = 0; m < 4; ++m)
            #pragma unroll
            for (int n = 0; n < 4; ++n)
                #pragma unroll
                for (int j = 0; j < 4; ++j) {
                    int row = brow + wm * 64 + m * 16 + (lane >> 4) * 4 + j;
                    if (row < N) {
                        int col = wn * 64 + n * 16 + (lane & 15);
                        hres[(long long)row * 128 + col] = acc[m][n][j];
                    }
                }
    }
}

// ---------------- bucket: group edges by dst, storing SRC node id (w recomputed in agg)
__global__ void bucket_kernel(const int* __restrict__ src, const int* __restrict__ dst,
                              int* __restrict__ cnt, int* __restrict__ bucket, int E) {
    int e = blockIdx.x * blockDim.x + threadIdx.x;
    if (e >= E) return;
    int sN = src[e], dN = dst[e];
    int idx = atomicAdd(cnt + dN, 1);
    if (idx < CAP) bucket[dN * CAP + idx] = sN;
}

// ---------------- agg v3: head-across-lanes. lane = hh*8+cc: head hh, dims [cc*16, cc*16+16).
// Per edge: 2 dwordx4 feat loads + 1 exp (vs 8) + 16 FMA. Butterfly over heads at node end.
__global__ __launch_bounds__(256) void agg_kernel(
    const unsigned short* __restrict__ featb,
    const float* __restrict__ el, const float* __restrict__ er,
    const int* __restrict__ cnt, const int* __restrict__ bucket,
    const float* __restrict__ hres, const float* __restrict__ bias_sum,
    unsigned short* __restrict__ hbf, float* __restrict__ partial, int N) {
    const int lane = threadIdx.x & 63;
    const int wv = threadIdx.x >> 6;
    const int hh = lane >> 3;       // head 0..7
    const int cc = lane & 7;        // dim-chunk 0..7 (16 dims each)
    const int d0 = lane * 2;
    __shared__ float hsh[4][128];   // wave-private h staging (no cross-wave use)
    __shared__ float red[4][64][4];
    float psum0 = 0.f, psq0 = 0.f, psum1 = 0.f, psq1 = 0.f;
    for (int n = blockIdx.x * 4 + wv; n < N; n += gridDim.x * 4) {
        const float erv = er[n * 8 + hh];
        int c = cnt[n]; if (c > CAP) c = CAP;
        float sden = 0.f;
        float acc[16];
        #pragma unroll
        for (int k = 0; k < 16; ++k) acc[k] = 0.f;
        // 1-deep prefetch of index + feat row + el
        uint4 f0n = {0,0,0,0}, f1n = {0,0,0,0};
        float eln = 0.f;
        if (c > 0) {
            int sn0 = bucket[n * CAP];
            const unsigned short* fb = featb + (long long)sn0 * 1024 + hh * 128 + cc * 16;
            f0n = *(const uint4*)(fb);
            f1n = *(const uint4*)(fb + 8);
            eln = el[sn0 * 8 + hh];
        }
        for (int i = 0; i < c; ++i) {
            uint4 f0 = f0n, f1 = f1n;
            float elv = eln;
            if (i + 1 < c) {
                int sn2 = bucket[n * CAP + i + 1];
                const unsigned short* fb2 = featb + (long long)sn2 * 1024 + hh * 128 + cc * 16;
                f0n = *(const uint4*)(fb2);
                f1n = *(const uint4*)(fb2 + 8);
                eln = el[sn2 * 8 + hh];
            }
            float v = elv + erv;                  // pre-scaled by log2(e)
            v = fmaxf(v, 0.2f * v);               // leaky_relu
            float w = __builtin_exp2f(v);         // one exp per edge per lane
            sden += w;
            unsigned int uu0 = f0.x, uu1 = f0.y, uu2 = f0.z, uu3 = f0.w;
            unsigned int uu4 = f1.x, uu5 = f1.y, uu6 = f1.z, uu7 = f1.w;
            union { unsigned int i; float f; } t;
            t.i = uu0 << 16;        acc[0]  += w * t.f;
            t.i = uu0 & 0xffff0000u; acc[1]  += w * t.f;
            t.i = uu1 << 16;        acc[2]  += w * t.f;
            t.i = uu1 & 0xffff0000u; acc[3]  += w * t.f;
            t.i = uu2 << 16;        acc[4]  += w * t.f;
            t.i = uu2 & 0xffff0000u; acc[5]  += w * t.f;
            t.i = uu3 << 16;        acc[6]  += w * t.f;
            t.i = uu3 & 0xffff0000u; acc[7]  += w * t.f;
            t.i = uu4 << 16;        acc[8]  += w * t.f;
            t.i = uu4 & 0xffff0000u; acc[9]  += w * t.f;
            t.i = uu5 << 16;        acc[10] += w * t.f;
            t.i = uu5 & 0xffff0000u; acc[11] += w * t.f;
            t.i = uu6 << 16;        acc[12] += w * t.f;
            t.i = uu6 & 0xffff0000u; acc[13] += w * t.f;
            t.i = uu7 << 16;        acc[14] += w * t.f;
            t.i = uu7 & 0xffff0000u; acc[15] += w * t.f;
        }
        // per-head alpha normalization, then butterfly-sum over the 8 head groups
        float inv = (c > 0) ? (1.f / sden) : 0.f;
        #pragma unroll
        for (int k = 0; k < 16; ++k) acc[k] *= inv;
        #pragma unroll
        for (int off = 8; off <= 32; off <<= 1) {
            #pragma unroll
            for (int k = 0; k < 16; ++k) acc[k] += __shfl_xor(acc[k], off, 64);
        }
        // head-0 lane group holds the head-summed values; stage via wave-private LDS
        if (hh == 0) {
            #pragma unroll
            for (int k = 0; k < 16; ++k) hsh[wv][cc * 16 + k] = acc[k];
        }
        __builtin_amdgcn_wave_barrier();   // same-wave LDS RAW; compiler inserts lgkmcnt
        float h0 = hsh[wv][d0]     + hres[(long long)n * 128 + d0]     + bias_sum[d0];
        float h1 = hsh[wv][d0 + 1] + hres[(long long)n * 128 + d0 + 1] + bias_sum[d0 + 1];
        __builtin_amdgcn_wave_barrier();   // keep next iter's LDS write after these reads
        h0 = h0 > 0.f ? h0 : 0.f;
        h1 = h1 > 0.f ? h1 : 0.f;
        unsigned int pack = (unsigned int)f2bf(h0) | ((unsigned int)f2bf(h1) << 16);
        *(unsigned int*)(hbf + (long long)n * 128 + d0) = pack;
        psum0 += h0; psq0 += h0 * h0; psum1 += h1; psq1 += h1 * h1;
    }
    red[wv][lane][0] = psum0; red[wv][lane][1] = psq0;
    red[wv][lane][2] = psum1; red[wv][lane][3] = psq1;
    __syncthreads();
    if (wv == 0) {
        float t0 = 0.f, t1 = 0.f, t2 = 0.f, t3 = 0.f;
        #pragma unroll
        for (int k = 0; k < 4; ++k) {
            t0 += red[k][lane][0]; t1 += red[k][lane][1];
            t2 += red[k][lane][2]; t3 += red[k][lane][3];
        }
        *(float4*)(partial + (blockIdx.x * 64 + lane) * 4) = make_float4(t0, t1, t2, t3);
    }
}

// ---------------- reduce: partial[AGGB][256] -> fin[256] via 64 blocks + atomics
__global__ __launch_bounds__(256) void reduce_kernel(const float* __restrict__ partial,
                                                     float* __restrict__ fin, int nblk) {
    const int t = threadIdx.x;
    const int rows = (nblk + gridDim.x - 1) / gridDim.x;
    const int b0 = blockIdx.x * rows;
    float a0 = 0.f, a1 = 0.f, a2 = 0.f, a3 = 0.f;
    for (int u = 0; u + 3 < rows; u += 4) {
        int bb = b0 + u;
        if (bb + 3 < nblk) {
            a0 += partial[(long long)bb * 256 + t];
            a1 += partial[(long long)(bb + 1) * 256 + t];
            a2 += partial[(long long)(bb + 2) * 256 + t];
            a3 += partial[(long long)(bb + 3) * 256 + t];
        } else {
            for (int k = 0; k < 4 && bb + k < nblk; ++k) a0 += partial[(long long)(bb + k) * 256 + t];
        }
    }
    for (int u = rows & ~3; u < rows; ++u)
        if (b0 + u < nblk) a0 += partial[(long long)(b0 + u) * 256 + t];
    fatomic_add(fin + t, (a0 + a1) + (a2 + a3));
}

// ---------------- fold: BN scale/shift -> bf16 folded weights Wcat[col][k] + fp32 folded biases
__global__ __launch_bounds__(1024) void fold_kernel(
    const float* __restrict__ fin,
    const float* __restrict__ gamma, const float* __restrict__ beta,
    const float* __restrict__ muW, const float* __restrict__ mub,
    const float* __restrict__ lsW, const float* __restrict__ lsb,
    unsigned short* __restrict__ wcat, float* __restrict__ bcat, int N) {
    __shared__ float sc_s[128], sh_s[128];
    __shared__ float redA[1024];
    const int t = threadIdx.x;
    if (t < 128) {
        float sum = fin[(t >> 1) * 4 + (t & 1) * 2];
        float sq  = fin[(t >> 1) * 4 + (t & 1) * 2 + 1];
        float mean = sum / (float)N;
        float var = sq / (float)N - mean * mean;        // biased var, matches jnp.var
        float rs = rsqrtf(var + 1e-5f);
        float sc = rs * gamma[t];
        sc_s[t] = sc;
        sh_s[t] = beta[t] - mean * sc;
    }
    __syncthreads();
    // wcat[c*128 + d] = bf16(sc[d] * W[d][c'])  (B-operand layout: [col][k])
    for (int i = t; i < 128 * 128; i += 1024) {
        int cc = i >> 7, d = i & 127;
        float wsrc = (cc < 64) ? muW[d * 64 + cc] : lsW[d * 64 + (cc - 64)];
        wcat[i] = f2bf(sc_s[d] * wsrc);
    }
    // bcat[c] = b[c'] + sum_d sh[d]*W[d][c']  -- 8 d-chunks x 128 cols, LDS reduce
    {
        int cc = t & 127, dc = t >> 7;
        float a = 0.f;
        #pragma unroll
        for (int u = 0; u < 16; ++u) {
            int d = dc * 16 + u;
            float wsrc = (cc < 64) ? muW[d * 64 + cc] : lsW[d * 64 + (cc - 64)];
            a += sh_s[d] * wsrc;
        }
        redA[t] = a;
    }
    __syncthreads();
    if (t < 128) {
        float b = (t < 64) ? mub[t] : lsb[t - 64];
        #pragma unroll
        for (int k = 0; k < 8; ++k) b += redA[k * 128 + t];
        bcat[t] = b;
    }
}

// ---------------- outgemm (MFMA): [mu|log_sigma] = hbf @ wcat + bcat, clip on ls half
__global__ __launch_bounds__(256) void outgemm_kernel(
    const unsigned short* __restrict__ hbf,   // [NPAD][128] bf16
    const unsigned short* __restrict__ wcat,  // [128 cols][128 k] bf16
    const float* __restrict__ bcat,           // [128]
    float* __restrict__ out, int N) {
    __shared__ unsigned short As[128 * 64];
    __shared__ unsigned short Bs[128 * 64];
    const int tid = threadIdx.x;
    const int lane = tid & 63;
    const int wid = tid >> 6;
    const int wm = wid >> 1, wn = wid & 1;
    const int brow = blockIdx.x * 128;

    f32x4 acc[4][4] = {};
    for (int kt = 0; kt < 2; ++kt) {
        #pragma unroll
        for (int it = 0; it < 4; ++it) {
            int c = it * 256 + tid;            // 16B chunk id, 0..1023
            int row = c >> 3, kc = c & 7;
            gload_lds16(hbf + (brow + row) * 128 + kt * 64 + kc * 8, (char*)As + c * 16);
            gload_lds16(wcat + row * 128 + kt * 64 + kc * 8,          (char*)Bs + c * 16);
        }
        __syncthreads();
        #pragma unroll
        for (int ks = 0; ks < 2; ++ks) {
            s16x8 a[4], b[4];
            #pragma unroll
            for (int m = 0; m < 4; ++m)
                a[m] = *(const s16x8*)(As + (wm * 64 + m * 16 + (lane & 15)) * 64 + ks * 32 + (lane >> 4) * 8);
            #pragma unroll
            for (int n = 0; n < 4; ++n)
                b[n] = *(const s16x8*)(Bs + (wn * 64 + n * 16 + (lane & 15)) * 64 + ks * 32 + (lane >> 4) * 8);
            #pragma unroll
            for (int m = 0; m < 4; ++m)
                #pragma unroll
                for (int n = 0; n < 4; ++n)
                    acc[m][n] = __builtin_amdgcn_mfma_f32_16x16x32_bf16(a[m], b[n], acc[m][n], 0, 0, 0);
        }
        __syncthreads();
    }

    float bc[4];
    #pragma unroll
    for (int n = 0; n < 4; ++n) bc[n] = bcat[wn * 64 + n * 16 + (lane & 15)];
    #pragma unroll
    for (int m = 0; m < 4; ++m)
        #pragma unroll
        for (int n = 0; n < 4; ++n) {
            int col = wn * 64 + n * 16 + (lane & 15);
            #pragma unroll
            for (int j = 0; j < 4; ++j) {
                int row = brow + wm * 64 + m * 16 + (lane >> 4) * 4 + j;
                if (row < N) {
                    float v = acc[m][n][j] + bc[n];
                    if (col < 64) {
                        out[(long long)row * 64 + col] = v;
                    } else {
                        v = fminf(fmaxf(v, -10.f), 10.f);
                        out[(long long)N * 64 + (long long)row * 64 + (col - 64)] = v;
                    }
                }
            }
        }
}

extern "C" void kernel_launch(void* const* d_in, const int* in_sizes, int n_in,
                              void* d_out, int out_size, void* d_ws, size_t ws_size,
                              hipStream_t stream) {
    const float* x      = (const float*)d_in[0];
    const float* W      = (const float*)d_in[1];
    const float* attn_l = (const float*)d_in[2];
    const float* attn_r = (const float*)d_in[3];
    const float* resW   = (const float*)d_in[4];
    const float* bias   = (const float*)d_in[5];
    const float* gamma  = (const float*)d_in[6];
    const float* beta   = (const float*)d_in[7];
    const float* muW    = (const float*)d_in[8];
    const float* mub    = (const float*)d_in[9];
    const float* lsW    = (const float*)d_in[10];
    const float* lsb    = (const float*)d_in[11];
    const int*   src    = (const int*)d_in[12];
    const int*   dst    = (const int*)d_in[13];

    const int N = in_sizes[0] / XD;
    const int E = in_sizes[12];
    const int NPAD = ((N + 127) / 128) * 128;

    char* p = (char*)d_ws;
    size_t off = 0;
    auto alloc = [&](size_t bytes) -> void* {
        void* r = p + off;
        off = (off + bytes + 255) & ~(size_t)255;
        return r;
    };
    unsigned short* xb   = (unsigned short*)alloc((size_t)NPAD * XD * 2);
    unsigned short* wtb  = (unsigned short*)alloc((size_t)XD * HH * DD * 2);
    unsigned short* rwtb = (unsigned short*)alloc((size_t)DD * XD * 2);
    float* bias_sum      = (float*)alloc(DD * 4);
    unsigned short* featb= (unsigned short*)alloc((size_t)N * HH * DD * 2);
    float* hres          = (float*)alloc((size_t)N * DD * 4);
    float* el            = (float*)alloc((size_t)N * HH * 4);   // zero region start
    float* er            = (float*)alloc((size_t)N * HH * 4);
    int*   cnt           = (int*)alloc((size_t)N * 4);
    float* fin           = (float*)alloc(256 * 4);              // zero region end
    int*   bucket        = (int*)alloc((size_t)N * CAP * 4);
    unsigned short* hbf  = (unsigned short*)alloc((size_t)NPAD * DD * 2);
    float* partial       = (float*)alloc((size_t)AGGB * 256 * 4);
    unsigned short* wcat = (unsigned short*)alloc(128 * 128 * 2);
    float* bcat          = (float*)alloc(128 * 4);

    // zero el|er|cnt|fin (exact byte span, alloc-rounding included)
    size_t zbytes = (size_t)((char*)bucket - (char*)el);
    hipMemsetAsync(el, 0, zbytes, stream);

    long long prep_total = (long long)NPAD * XD / 4 + XD * HH * DD + DD * XD + DD;
    int prep_blocks = (int)((prep_total + 255) / 256);
    prep_kernel<<<prep_blocks, 256, 0, stream>>>(x, W, resW, bias, xb, wtb, rwtb, bias_sum, N, NPAD);

    dim3 g1(NPAD / 128, HH + 1);
    gemm1_kernel<<<g1, 256, 0, stream>>>(xb, wtb, rwtb, attn_l, attn_r, featb, hres, el, er, N);

    bucket_kernel<<<(E + 255) / 256, 256, 0, stream>>>(src, dst, cnt, bucket, E);

    agg_kernel<<<AGGB, 256, 0, stream>>>(featb, el, er, cnt, bucket, hres, bias_sum,
                                         hbf, partial, N);

    reduce_kernel<<<REDB, 256, 0, stream>>>(partial, fin, AGGB);

    fold_kernel<<<1, 1024, 0, stream>>>(fin, gamma, beta, muW, mub, lsW, lsb, wcat, bcat, N);

    outgemm_kernel<<<NPAD / 128, 256, 0, stream>>>(hbf, wcat, bcat, (float*)d_out, N);
}

// Round 14
// 248.804 us; speedup vs baseline: 1.0155x; 1.0097x over previous
//
#include <hip/hip_runtime.h>
#include <hip/hip_bf16.h>

#define XD 256   // input feature dim
#define HH 8     // heads
#define DD 128   // per-head dim
#define ZD 64    // latent dim
#define CAP 64   // max in-degree bucket capacity (mean deg=9, P(>=64) ~ 1e-30)
#define AGGB 2048 // blocks for aggregation kernel (8192 waves = 32/CU, HW cap)
#define REDB 64   // blocks for partial-reduce kernel
#define LOG2E 1.44269504088896340736f

using f32x4 = __attribute__((ext_vector_type(4))) float;
using s16x8 = __attribute__((ext_vector_type(8))) short;

static __device__ __forceinline__ float bf2f(unsigned short u) {
    union { unsigned int i; float f; } v; v.i = ((unsigned int)u) << 16; return v.f;
}
static __device__ __forceinline__ unsigned short f2bf(float f) {
    union { float f; unsigned int i; } v; v.f = f;
    unsigned int r = v.i + 0x7FFFu + ((v.i >> 16) & 1u);  // round-to-nearest-even
    return (unsigned short)(r >> 16);
}
static __device__ __forceinline__ void gload_lds16(const void* g, void* l) {
    __builtin_amdgcn_global_load_lds(
        (const __attribute__((address_space(1))) unsigned int*)g,
        (__attribute__((address_space(3))) unsigned int*)l, 16, 0, 0);
}
static __device__ __forceinline__ void fatomic_add(float* p, float v) {
    __hip_atomic_fetch_add(p, v, __ATOMIC_RELAXED, __HIP_MEMORY_SCOPE_AGENT);
}

// ---------------- prep: x->bf16 (padded), W->W^T bf16, res_W -> head-summed ^T bf16, bias head-sum
__global__ void prep_kernel(const float* __restrict__ x, const float* __restrict__ W,
                            const float* __restrict__ resW, const float* __restrict__ bias,
                            unsigned short* __restrict__ xb, unsigned short* __restrict__ wtb,
                            unsigned short* __restrict__ rwtb, float* __restrict__ bias_sum,
                            int N, int NPAD) {
    long long i = (long long)blockIdx.x * blockDim.x + threadIdx.x;
    long long nx4 = (long long)NPAD * XD / 4;
    if (i < nx4) {
        long long e = i * 4;
        long long lim = (long long)N * XD;
        float4 v = {0.f, 0.f, 0.f, 0.f};
        if (e < lim) v = *(const float4*)(x + e);  // N*XD is a multiple of 4
        ushort4 o; o.x = f2bf(v.x); o.y = f2bf(v.y); o.z = f2bf(v.z); o.w = f2bf(v.w);
        *(ushort4*)(xb + e) = o;
        return;
    }
    i -= nx4;
    if (i < XD * HH * DD) {        // W^T: wtb[col][k] = W[k][col]
        int col = (int)(i >> 8), k = (int)(i & 255);
        wtb[i] = f2bf(W[(long long)k * (HH * DD) + col]);
        return;
    }
    i -= XD * HH * DD;
    if (i < DD * XD) {             // rwtb[d][k] = sum_h resW[k][h*DD+d]
        int d = (int)(i >> 8), k = (int)(i & 255);
        float s = 0.f;
        #pragma unroll
        for (int h = 0; h < HH; ++h) s += resW[(long long)k * (HH * DD) + h * DD + d];
        rwtb[i] = f2bf(s);
        return;
    }
    i -= DD * XD;
    if (i < DD) {
        float s = 0.f;
        #pragma unroll
        for (int h = 0; h < HH; ++h) s += bias[h * DD + (int)i];
        bias_sum[i] = s;
    }
}

// ---------------- gemm1: feat = x@W (bf16 out) + el/er epilogue; blockIdx.y==8 -> hres = x@res_W_sum
// NOTE: el/er are accumulated PRE-SCALED by log2(e) so agg can use exp2 directly.
__global__ __launch_bounds__(256) void gemm1_kernel(
    const unsigned short* __restrict__ xb,    // [NPAD][256] bf16
    const unsigned short* __restrict__ wtb,   // [1024][256] bf16 (W^T)
    const unsigned short* __restrict__ rwtb,  // [128][256]  bf16 (res_W_sum^T)
    const float* __restrict__ attn_l, const float* __restrict__ attn_r,  // [8][128]
    unsigned short* __restrict__ featb,       // [N][1024] bf16
    float* __restrict__ hres,                 // [N][128]
    float* __restrict__ el, float* __restrict__ er,  // [N][8] (atomic accum, pre-zeroed)
    int N) {
    __shared__ unsigned short As[128 * 64];
    __shared__ unsigned short Bs[128 * 64];
    const int tid = threadIdx.x;
    const int lane = tid & 63;
    const int wid = tid >> 6;
    const int wm = wid >> 1, wn = wid & 1;
    const int brow = blockIdx.x * 128;
    const int y = blockIdx.y;  // 0..7 = head blocks, 8 = residual block
    const unsigned short* bsrc = (y < 8) ? (wtb + y * 128 * 256) : rwtb;

    f32x4 acc[4][4] = {};
    for (int kt = 0; kt < 4; ++kt) {
        #pragma unroll
        for (int it = 0; it < 4; ++it) {
            int c = it * 256 + tid;            // 16B chunk id, 0..1023
            int row = c >> 3, kc = c & 7;
            gload_lds16(xb  + (brow + row) * 256 + kt * 64 + kc * 8, (char*)As + c * 16);
            gload_lds16(bsrc + row * 256 + kt * 64 + kc * 8,          (char*)Bs + c * 16);
        }
        __syncthreads();
        #pragma unroll
        for (int ks = 0; ks < 2; ++ks) {
            s16x8 a[4], b[4];
            #pragma unroll
            for (int m = 0; m < 4; ++m)
                a[m] = *(const s16x8*)(As + (wm * 64 + m * 16 + (lane & 15)) * 64 + ks * 32 + (lane >> 4) * 8);
            #pragma unroll
            for (int n = 0; n < 4; ++n)
                b[n] = *(const s16x8*)(Bs + (wn * 64 + n * 16 + (lane & 15)) * 64 + ks * 32 + (lane >> 4) * 8);
            #pragma unroll
            for (int m = 0; m < 4; ++m)
                #pragma unroll
                for (int n = 0; n < 4; ++n)
                    acc[m][n] = __builtin_amdgcn_mfma_f32_16x16x32_bf16(a[m], b[n], acc[m][n], 0, 0, 0);
        }
        __syncthreads();
    }

    if (y < 8) {
        float al[4], ar[4];
        #pragma unroll
        for (int n = 0; n < 4; ++n) {
            int colh = wn * 64 + n * 16 + (lane & 15);
            al[n] = attn_l[y * 128 + colh] * LOG2E;
            ar[n] = attn_r[y * 128 + colh] * LOG2E;
        }
        #pragma unroll
        for (int m = 0; m < 4; ++m) {
            #pragma unroll
            for (int j = 0; j < 4; ++j) {
                int row = brow + wm * 64 + m * 16 + (lane >> 4) * 4 + j;
                float pel = 0.f, per = 0.f;
                #pragma unroll
                for (int n = 0; n < 4; ++n) { pel += acc[m][n][j] * al[n]; per += acc[m][n][j] * ar[n]; }
                #pragma unroll
                for (int o = 1; o < 16; o <<= 1) { pel += __shfl_xor(pel, o); per += __shfl_xor(per, o); }
                if ((lane & 15) == 0 && row < N) {
                    fatomic_add(el + row * 8 + y, pel);
                    fatomic_add(er + row * 8 + y, per);
                }
            }
        }
        #pragma unroll
        for (int m = 0; m < 4; ++m)
            #pragma unroll
            for (int n = 0; n < 4; ++n)
                #pragma unroll
                for (int j = 0; j < 4; ++j) {
                    int row = brow + wm * 64 + m * 16 + (lane >> 4) * 4 + j;
                    if (row < N) {
                        int col = y * 128 + wn * 64 + n * 16 + (lane & 15);
                        featb[(long long)row * 1024 + col] = f2bf(acc[m][n][j]);
                    }
                }
    } else {
        #pragma unroll
        for (int m = 0; m < 4; ++m)
            #pragma unroll
            for (int n = 0; n < 4; ++n)
                #pragma unroll
                for (int j = 0; j < 4; ++j) {
                    int row = brow + wm * 64 + m * 16 + (lane >> 4) * 4 + j;
                    if (row < N) {
                        int col = wn * 64 + n * 16 + (lane & 15);
                        hres[(long long)row * 128 + col] = acc[m][n][j];
                    }
                }
    }
}

// ---------------- bucket: group edges by dst, storing SRC node id (w recomputed in agg)
__global__ void bucket_kernel(const int* __restrict__ src, const int* __restrict__ dst,
                              int* __restrict__ cnt, int* __restrict__ bucket, int E) {
    int e = blockIdx.x * blockDim.x + threadIdx.x;
    if (e >= E) return;
    int sN = src[e], dN = dst[e];
    int idx = atomicAdd(cnt + dN, 1);
    if (idx < CAP) bucket[dN * CAP + idx] = sN;
}

// ---------------- agg v4: head-across-lanes + 2-deep feat / 3-deep bucket prefetch pipeline.
__global__ __launch_bounds__(256) void agg_kernel(
    const unsigned short* __restrict__ featb,
    const float* __restrict__ el, const float* __restrict__ er,
    const int* __restrict__ cnt, const int* __restrict__ bucket,
    const float* __restrict__ hres, const float* __restrict__ bias_sum,
    unsigned short* __restrict__ hbf, float* __restrict__ partial, int N) {
    const int lane = threadIdx.x & 63;
    const int wv = threadIdx.x >> 6;
    const int hh = lane >> 3;       // head 0..7
    const int cc = lane & 7;        // dim-chunk 0..7 (16 dims each)
    const int d0 = lane * 2;
    __shared__ float hsh[4][128];   // wave-private h staging (no cross-wave use)
    __shared__ float red[4][64][4];
    float psum0 = 0.f, psq0 = 0.f, psum1 = 0.f, psq1 = 0.f;
    for (int n = blockIdx.x * 4 + wv; n < N; n += gridDim.x * 4) {
        const float erv = er[n * 8 + hh];
        int c = cnt[n]; if (c > CAP) c = CAP;
        float sden = 0.f;
        float acc[16];
        #pragma unroll
        for (int k = 0; k < 16; ++k) acc[k] = 0.f;
        // pipeline: A = edge i data, B = edge i+1 data, snC = src of edge i+2
        uint4 fA0 = {0,0,0,0}, fA1 = {0,0,0,0}, fB0 = {0,0,0,0}, fB1 = {0,0,0,0};
        float elA = 0.f, elB = 0.f;
        int snC = 0;
        if (c > 0) {
            int s0 = bucket[n * CAP];
            const unsigned short* fb = featb + (long long)s0 * 1024 + hh * 128 + cc * 16;
            fA0 = *(const uint4*)(fb);
            fA1 = *(const uint4*)(fb + 8);
            elA = el[s0 * 8 + hh];
        }
        if (c > 1) {
            int s1 = bucket[n * CAP + 1];
            const unsigned short* fb = featb + (long long)s1 * 1024 + hh * 128 + cc * 16;
            fB0 = *(const uint4*)(fb);
            fB1 = *(const uint4*)(fb + 8);
            elB = el[s1 * 8 + hh];
        }
        if (c > 2) snC = bucket[n * CAP + 2];
        for (int i = 0; i < c; ++i) {
            uint4 f0 = fA0, f1 = fA1;
            float elv = elA;
            // shift pipeline: A <= B, B <= feat(snC), snC <= bucket[i+3]
            fA0 = fB0; fA1 = fB1; elA = elB;
            if (i + 2 < c) {
                const unsigned short* fb2 = featb + (long long)snC * 1024 + hh * 128 + cc * 16;
                fB0 = *(const uint4*)(fb2);
                fB1 = *(const uint4*)(fb2 + 8);
                elB = el[snC * 8 + hh];
            }
            if (i + 3 < c) snC = bucket[n * CAP + i + 3];
            float v = elv + erv;                  // pre-scaled by log2(e)
            v = fmaxf(v, 0.2f * v);               // leaky_relu
            float w = __builtin_exp2f(v);         // one exp per edge per lane
            sden += w;
            unsigned int uu0 = f0.x, uu1 = f0.y, uu2 = f0.z, uu3 = f0.w;
            unsigned int uu4 = f1.x, uu5 = f1.y, uu6 = f1.z, uu7 = f1.w;
            union { unsigned int i; float f; } t;
            t.i = uu0 << 16;        acc[0]  += w * t.f;
            t.i = uu0 & 0xffff0000u; acc[1]  += w * t.f;
            t.i = uu1 << 16;        acc[2]  += w * t.f;
            t.i = uu1 & 0xffff0000u; acc[3]  += w * t.f;
            t.i = uu2 << 16;        acc[4]  += w * t.f;
            t.i = uu2 & 0xffff0000u; acc[5]  += w * t.f;
            t.i = uu3 << 16;        acc[6]  += w * t.f;
            t.i = uu3 & 0xffff0000u; acc[7]  += w * t.f;
            t.i = uu4 << 16;        acc[8]  += w * t.f;
            t.i = uu4 & 0xffff0000u; acc[9]  += w * t.f;
            t.i = uu5 << 16;        acc[10] += w * t.f;
            t.i = uu5 & 0xffff0000u; acc[11] += w * t.f;
            t.i = uu6 << 16;        acc[12] += w * t.f;
            t.i = uu6 & 0xffff0000u; acc[13] += w * t.f;
            t.i = uu7 << 16;        acc[14] += w * t.f;
            t.i = uu7 & 0xffff0000u; acc[15] += w * t.f;
        }
        // per-head alpha normalization, then butterfly-sum over the 8 head groups
        float inv = (c > 0) ? (1.f / sden) : 0.f;
        #pragma unroll
        for (int k = 0; k < 16; ++k) acc[k] *= inv;
        #pragma unroll
        for (int off = 8; off <= 32; off <<= 1) {
            #pragma unroll
            for (int k = 0; k < 16; ++k) acc[k] += __shfl_xor(acc[k], off, 64);
        }
        // head-0 lane group holds the head-summed values; stage via wave-private LDS
        if (hh == 0) {
            #pragma unroll
            for (int k = 0; k < 16; ++k) hsh[wv][cc * 16 + k] = acc[k];
        }
        __builtin_amdgcn_wave_barrier();   // same-wave LDS RAW; compiler inserts lgkmcnt
        float h0 = hsh[wv][d0]     + hres[(long long)n * 128 + d0]     + bias_sum[d0];
        float h1 = hsh[wv][d0 + 1] + hres[(long long)n * 128 + d0 + 1] + bias_sum[d0 + 1];
        __builtin_amdgcn_wave_barrier();   // keep next iter's LDS write after these reads
        h0 = h0 > 0.f ? h0 : 0.f;
        h1 = h1 > 0.f ? h1 : 0.f;
        unsigned int pack = (unsigned int)f2bf(h0) | ((unsigned int)f2bf(h1) << 16);
        *(unsigned int*)(hbf + (long long)n * 128 + d0) = pack;
        psum0 += h0; psq0 += h0 * h0; psum1 += h1; psq1 += h1 * h1;
    }
    red[wv][lane][0] = psum0; red[wv][lane][1] = psq0;
    red[wv][lane][2] = psum1; red[wv][lane][3] = psq1;
    __syncthreads();
    if (wv == 0) {
        float t0 = 0.f, t1 = 0.f, t2 = 0.f, t3 = 0.f;
        #pragma unroll
        for (int k = 0; k < 4; ++k) {
            t0 += red[k][lane][0]; t1 += red[k][lane][1];
            t2 += red[k][lane][2]; t3 += red[k][lane][3];
        }
        *(float4*)(partial + (blockIdx.x * 64 + lane) * 4) = make_float4(t0, t1, t2, t3);
    }
}

// ---------------- reduce: partial[AGGB][256] -> fin[256] via 64 blocks + atomics
__global__ __launch_bounds__(256) void reduce_kernel(const float* __restrict__ partial,
                                                     float* __restrict__ fin, int nblk) {
    const int t = threadIdx.x;
    const int rows = (nblk + gridDim.x - 1) / gridDim.x;
    const int b0 = blockIdx.x * rows;
    float a0 = 0.f, a1 = 0.f, a2 = 0.f, a3 = 0.f;
    for (int u = 0; u + 3 < rows; u += 4) {
        int bb = b0 + u;
        if (bb + 3 < nblk) {
            a0 += partial[(long long)bb * 256 + t];
            a1 += partial[(long long)(bb + 1) * 256 + t];
            a2 += partial[(long long)(bb + 2) * 256 + t];
            a3 += partial[(long long)(bb + 3) * 256 + t];
        } else {
            for (int k = 0; k < 4 && bb + k < nblk; ++k) a0 += partial[(long long)(bb + k) * 256 + t];
        }
    }
    for (int u = rows & ~3; u < rows; ++u)
        if (b0 + u < nblk) a0 += partial[(long long)(b0 + u) * 256 + t];
    fatomic_add(fin + t, (a0 + a1) + (a2 + a3));
}

// ---------------- fold: BN scale/shift -> bf16 folded weights Wcat[col][k] + fp32 folded biases
__global__ __launch_bounds__(1024) void fold_kernel(
    const float* __restrict__ fin,
    const float* __restrict__ gamma, const float* __restrict__ beta,
    const float* __restrict__ muW, const float* __restrict__ mub,
    const float* __restrict__ lsW, const float* __restrict__ lsb,
    unsigned short* __restrict__ wcat, float* __restrict__ bcat, int N) {
    __shared__ float sc_s[128], sh_s[128];
    __shared__ float redA[1024];
    const int t = threadIdx.x;
    if (t < 128) {
        float sum = fin[(t >> 1) * 4 + (t & 1) * 2];
        float sq  = fin[(t >> 1) * 4 + (t & 1) * 2 + 1];
        float mean = sum / (float)N;
        float var = sq / (float)N - mean * mean;        // biased var, matches jnp.var
        float rs = rsqrtf(var + 1e-5f);
        float sc = rs * gamma[t];
        sc_s[t] = sc;
        sh_s[t] = beta[t] - mean * sc;
    }
    __syncthreads();
    // wcat[c*128 + d] = bf16(sc[d] * W[d][c'])  (B-operand layout: [col][k])
    for (int i = t; i < 128 * 128; i += 1024) {
        int cc = i >> 7, d = i & 127;
        float wsrc = (cc < 64) ? muW[d * 64 + cc] : lsW[d * 64 + (cc - 64)];
        wcat[i] = f2bf(sc_s[d] * wsrc);
    }
    // bcat[c] = b[c'] + sum_d sh[d]*W[d][c']  -- 8 d-chunks x 128 cols, LDS reduce
    {
        int cc = t & 127, dc = t >> 7;
        float a = 0.f;
        #pragma unroll
        for (int u = 0; u < 16; ++u) {
            int d = dc * 16 + u;
            float wsrc = (cc < 64) ? muW[d * 64 + cc] : lsW[d * 64 + (cc - 64)];
            a += sh_s[d] * wsrc;
        }
        redA[t] = a;
    }
    __syncthreads();
    if (t < 128) {
        float b = (t < 64) ? mub[t] : lsb[t - 64];
        #pragma unroll
        for (int k = 0; k < 8; ++k) b += redA[k * 128 + t];
        bcat[t] = b;
    }
}

// ---------------- outgemm (MFMA): [mu|log_sigma] = hbf @ wcat + bcat, clip on ls half
__global__ __launch_bounds__(256) void outgemm_kernel(
    const unsigned short* __restrict__ hbf,   // [NPAD][128] bf16
    const unsigned short* __restrict__ wcat,  // [128 cols][128 k] bf16
    const float* __restrict__ bcat,           // [128]
    float* __restrict__ out, int N) {
    __shared__ unsigned short As[128 * 64];
    __shared__ unsigned short Bs[128 * 64];
    const int tid = threadIdx.x;
    const int lane = tid & 63;
    const int wid = tid >> 6;
    const int wm = wid >> 1, wn = wid & 1;
    const int brow = blockIdx.x * 128;

    f32x4 acc[4][4] = {};
    for (int kt = 0; kt < 2; ++kt) {
        #pragma unroll
        for (int it = 0; it < 4; ++it) {
            int c = it * 256 + tid;            // 16B chunk id, 0..1023
            int row = c >> 3, kc = c & 7;
            gload_lds16(hbf + (brow + row) * 128 + kt * 64 + kc * 8, (char*)As + c * 16);
            gload_lds16(wcat + row * 128 + kt * 64 + kc * 8,          (char*)Bs + c * 16);
        }
        __syncthreads();
        #pragma unroll
        for (int ks = 0; ks < 2; ++ks) {
            s16x8 a[4], b[4];
            #pragma unroll
            for (int m = 0; m < 4; ++m)
                a[m] = *(const s16x8*)(As + (wm * 64 + m * 16 + (lane & 15)) * 64 + ks * 32 + (lane >> 4) * 8);
            #pragma unroll
            for (int n = 0; n < 4; ++n)
                b[n] = *(const s16x8*)(Bs + (wn * 64 + n * 16 + (lane & 15)) * 64 + ks * 32 + (lane >> 4) * 8);
            #pragma unroll
            for (int m = 0; m < 4; ++m)
                #pragma unroll
                for (int n = 0; n < 4; ++n)
                    acc[m][n] = __builtin_amdgcn_mfma_f32_16x16x32_bf16(a[m], b[n], acc[m][n], 0, 0, 0);
        }
        __syncthreads();
    }

    float bc[4];
    #pragma unroll
    for (int n = 0; n < 4; ++n) bc[n] = bcat[wn * 64 + n * 16 + (lane & 15)];
    #pragma unroll
    for (int m = 0; m < 4; ++m)
        #pragma unroll
        for (int n = 0; n < 4; ++n) {
            int col = wn * 64 + n * 16 + (lane & 15);
            #pragma unroll
            for (int j = 0; j < 4; ++j) {
                int row = brow + wm * 64 + m * 16 + (lane >> 4) * 4 + j;
                if (row < N) {
                    float v = acc[m][n][j] + bc[n];
                    if (col < 64) {
                        out[(long long)row * 64 + col] = v;
                    } else {
                        v = fminf(fmaxf(v, -10.f), 10.f);
                        out[(long long)N * 64 + (long long)row * 64 + (col - 64)] = v;
                    }
                }
            }
        }
}

extern "C" void kernel_launch(void* const* d_in, const int* in_sizes, int n_in,
                              void* d_out, int out_size, void* d_ws, size_t ws_size,
                              hipStream_t stream) {
    const float* x      = (const float*)d_in[0];
    const float* W      = (const float*)d_in[1];
    const float* attn_l = (const float*)d_in[2];
    const float* attn_r = (const float*)d_in[3];
    const float* resW   = (const float*)d_in[4];
    const float* bias   = (const float*)d_in[5];
    const float* gamma  = (const float*)d_in[6];
    const float* beta   = (const float*)d_in[7];
    const float* muW    = (const float*)d_in[8];
    const float* mub    = (const float*)d_in[9];
    const float* lsW    = (const float*)d_in[10];
    const float* lsb    = (const float*)d_in[11];
    const int*   src    = (const int*)d_in[12];
    const int*   dst    = (const int*)d_in[13];

    const int N = in_sizes[0] / XD;
    const int E = in_sizes[12];
    const int NPAD = ((N + 127) / 128) * 128;

    char* p = (char*)d_ws;
    size_t off = 0;
    auto alloc = [&](size_t bytes) -> void* {
        void* r = p + off;
        off = (off + bytes + 255) & ~(size_t)255;
        return r;
    };
    unsigned short* xb   = (unsigned short*)alloc((size_t)NPAD * XD * 2);
    unsigned short* wtb  = (unsigned short*)alloc((size_t)XD * HH * DD * 2);
    unsigned short* rwtb = (unsigned short*)alloc((size_t)DD * XD * 2);
    float* bias_sum      = (float*)alloc(DD * 4);
    unsigned short* featb= (unsigned short*)alloc((size_t)N * HH * DD * 2);
    float* hres          = (float*)alloc((size_t)N * DD * 4);
    float* el            = (float*)alloc((size_t)N * HH * 4);   // zero region start
    float* er            = (float*)alloc((size_t)N * HH * 4);
    int*   cnt           = (int*)alloc((size_t)N * 4);
    float* fin           = (float*)alloc(256 * 4);              // zero region end
    int*   bucket        = (int*)alloc((size_t)N * CAP * 4);
    unsigned short* hbf  = (unsigned short*)alloc((size_t)NPAD * DD * 2);
    float* partial       = (float*)alloc((size_t)AGGB * 256 * 4);
    unsigned short* wcat = (unsigned short*)alloc(128 * 128 * 2);
    float* bcat          = (float*)alloc(128 * 4);

    // zero el|er|cnt|fin (exact byte span, alloc-rounding included)
    size_t zbytes = (size_t)((char*)bucket - (char*)el);
    hipMemsetAsync(el, 0, zbytes, stream);

    long long prep_total = (long long)NPAD * XD / 4 + XD * HH * DD + DD * XD + DD;
    int prep_blocks = (int)((prep_total + 255) / 256);
    prep_kernel<<<prep_blocks, 256, 0, stream>>>(x, W, resW, bias, xb, wtb, rwtb, bias_sum, N, NPAD);

    dim3 g1(NPAD / 128, HH + 1);
    gemm1_kernel<<<g1, 256, 0, stream>>>(xb, wtb, rwtb, attn_l, attn_r, featb, hres, el, er, N);

    bucket_kernel<<<(E + 255) / 256, 256, 0, stream>>>(src, dst, cnt, bucket, E);

    agg_kernel<<<AGGB, 256, 0, stream>>>(featb, el, er, cnt, bucket, hres, bias_sum,
                                         hbf, partial, N);

    reduce_kernel<<<REDB, 256, 0, stream>>>(partial, fin, AGGB);

    fold_kernel<<<1, 1024, 0, stream>>>(fin, gamma, beta, muW, mub, lsW, lsb, wcat, bcat, N);

    outgemm_kernel<<<NPAD / 128, 256, 0, stream>>>(hbf, wcat, bcat, (float*)d_out, N);
}